// Round 19
// baseline (183.951 us; speedup 1.0000x reference)
//
#include <hip/hip_runtime.h>
#include <hip/hip_bf16.h>

#define BW 128
#define NTOK 343
#define DIMC 192
#define NHEAD 6
#define HDIM 32
#define TOK (BW * NTOK)      // 43904
#define M2 (2 * TOK)         // 87808
#define NN (NTOK * NTOK)     // 117649
#define BSTR 344             // padded bias row stride (16B-aligned float4 reads)
#define BNN (NTOK * BSTR)    // 117992 per head
#define QSCALE 0.17677669529663687f
#define LOG2E 1.4426950408889634f

typedef unsigned int uint32;
typedef __attribute__((ext_vector_type(8))) short short8;   // 8 bf16 = 4 VGPR
typedef __attribute__((ext_vector_type(4))) float f32x4;

// round-to-nearest-even f32 -> bf16 bits (scalar path)
__device__ __forceinline__ unsigned short f2bf(float f) {
  uint32 u = __float_as_uint(f);
  u += 0x7fffu + ((u >> 16) & 1u);
  return (unsigned short)(u >> 16);
}

// pair pack via v_cvt_pk_bf16_f32 (semantic form; casts beat hand bit-ops)
__device__ __forceinline__ uint32 pkpair(float a, float b) {
  __hip_bfloat162 h = __float22bfloat162_rn(make_float2(a, b));
  uint32 u;
  __builtin_memcpy(&u, &h, 4);
  return u;
}

__device__ __forceinline__ uint4 pack8bf(const float4 a, const float4 b) {
  uint4 pk;
  pk.x = pkpair(a.x, a.y);
  pk.y = pkpair(a.z, a.w);
  pk.z = pkpair(b.x, b.y);
  pk.w = pkpair(b.z, b.w);
  return pk;
}

// native 2^x (v_exp_f32); logits carry log2e factor so this IS softmax's exp
__device__ __forceinline__ float fexp2(float x) {
  float r;
  asm("v_exp_f32 %0, %1" : "=v"(r) : "v"(x));
  return r;
}

// PV k-permutation pi (dot-product k-order invariant; A and B agree):
// within each 32-block: l=(n&31), lo=l&15, hi=l>>4 -> slot (lo>>2)*8 + hi*4 + (lo&3)
__device__ __forceinline__ int vperm(int n) {
  const int base = n & ~31, l = n & 31, lo = l & 15, hi = l >> 4;
  return base + ((lo >> 2) << 3) + (hi << 2) + (lo & 3);
}

// ---------------- bias gather: bias[h][i][j] = rpb[rel_idx[i,j]*NH + h] * log2e ----------------
__global__ void k_bias(const float* __restrict__ rpb, const int* __restrict__ ridx,
                       float* __restrict__ biasws) {
  const int idx = blockIdx.x * 256 + threadIdx.x;
  if (idx < NN) {
    const int r = ridx[idx];
    const int i = idx / NTOK, j = idx % NTOK;
#pragma unroll
    for (int h = 0; h < NHEAD; ++h)
      biasws[h * BNN + i * BSTR + j] = rpb[r * NHEAD + h] * LOG2E;
  }
}

// ---------------- QKV projection: MFMA bf16, BM=128, async W prefetch (T14) ----------------
__global__ __launch_bounds__(256) void k_qkv(const float* __restrict__ x,
                                             const float* __restrict__ x1,
                                             const float* __restrict__ w,
                                             const float* __restrict__ bvec,
                                             unsigned short* __restrict__ qkvo) {
  __shared__ unsigned short Xs[128][200];   // 51.2 KB
  __shared__ unsigned short Ws[64][200];    // 25.6 KB
  const int R0 = blockIdx.x * 128;
  const int s = R0 / TOK;
  const int tokbase = R0 % TOK;
  const float* __restrict__ src = s ? x1 : x;
  const int tid = threadIdx.x;
  const int lane = tid & 63, wv = tid >> 6;
  const int c16 = lane & 15, q4 = lane >> 4;
  const int wr = wv >> 1, wc = wv & 1;      // wave: 64-row half x 32-col half

  int bidxv[4], nnv[4];
#pragma unroll
  for (int n = 0; n < 4; ++n) {
    const int tok = tokbase + wr * 64 + n * 16 + c16;
    bidxv[n] = tok / NTOK;
    nnv[n] = tok % NTOK;
  }

  for (int c = tid; c < 128 * 24; c += 256) {
    const int r = c / 24, k8 = (c % 24) * 8;
    const float* p = &src[(size_t)(tokbase + r) * DIMC + k8];
    const float4 a = *reinterpret_cast<const float4*>(p);
    const float4 b = *reinterpret_cast<const float4*>(p + 4);
    *reinterpret_cast<uint4*>(&Xs[r][k8]) = pack8bf(a, b);
  }

  float4 wa[6], wb[6];
#pragma unroll
  for (int i = 0; i < 6; ++i) {
    const int c = tid + i * 256;
    const int r = c / 24, k8 = (c % 24) * 8;
    const float* p = &w[(size_t)r * DIMC + k8];
    wa[i] = *reinterpret_cast<const float4*>(p);
    wb[i] = *reinterpret_cast<const float4*>(p + 4);
  }

  for (int ct = 0; ct < 9; ++ct) {
    __syncthreads();
#pragma unroll
    for (int i = 0; i < 6; ++i) {
      const int c = tid + i * 256;
      const int r = c / 24, k8 = (c % 24) * 8;
      *reinterpret_cast<uint4*>(&Ws[r][k8]) = pack8bf(wa[i], wb[i]);
    }
    __syncthreads();

    if (ct < 8) {
#pragma unroll
      for (int i = 0; i < 6; ++i) {
        const int c = tid + i * 256;
        const int r = c / 24, k8 = (c % 24) * 8;
        const float* p = &w[(size_t)((ct + 1) * 64 + r) * DIMC + k8];
        wa[i] = *reinterpret_cast<const float4*>(p);
        wb[i] = *reinterpret_cast<const float4*>(p + 4);
      }
    }

    const int colbase = ct * 64 + wc * 32;
    f32x4 acc[2][4];
#pragma unroll
    for (int m = 0; m < 2; ++m) {
      const float4 bb = *reinterpret_cast<const float4*>(&bvec[colbase + m * 16 + q4 * 4]);
#pragma unroll
      for (int n = 0; n < 4; ++n) acc[m][n] = f32x4{bb.x, bb.y, bb.z, bb.w};
    }
#pragma unroll
    for (int ks = 0; ks < 6; ++ks) {
      const short8 w0 = *reinterpret_cast<const short8*>(&Ws[wc * 32 + c16][ks * 32 + q4 * 8]);
      const short8 w1 = *reinterpret_cast<const short8*>(&Ws[wc * 32 + 16 + c16][ks * 32 + q4 * 8]);
      short8 xf[4];
#pragma unroll
      for (int n = 0; n < 4; ++n)
        xf[n] = *reinterpret_cast<const short8*>(&Xs[wr * 64 + n * 16 + c16][ks * 32 + q4 * 8]);
#pragma unroll
      for (int n = 0; n < 4; ++n) {
        acc[0][n] = __builtin_amdgcn_mfma_f32_16x16x32_bf16(w0, xf[n], acc[0][n], 0, 0, 0);
        acc[1][n] = __builtin_amdgcn_mfma_f32_16x16x32_bf16(w1, xf[n], acc[1][n], 0, 0, 0);
      }
    }

    const int t = ct / 3;
    const float qs = (t == 0) ? (QSCALE * LOG2E) : 1.0f;
#pragma unroll
    for (int m = 0; m < 2; ++m) {
      const int col0 = colbase + m * 16 + q4 * 4;
      const int h = (col0 - t * DIMC) / HDIM;
      const int d0 = col0 & (HDIM - 1);
      const size_t hb = ((size_t)(s * 3 + t) * BW) * NHEAD + h;
#pragma unroll
      for (int n = 0; n < 4; ++n) {
        const f32x4 a = acc[m][n];
        uint2 pk;
        pk.x = pkpair(a[0] * qs, a[1] * qs);
        pk.y = pkpair(a[2] * qs, a[3] * qs);
        const size_t ob = ((hb + (size_t)bidxv[n] * NHEAD) * NTOK + nnv[n]) * HDIM + d0;
        *reinterpret_cast<uint2*>(&qkvo[ob]) = pk;
      }
    }
  }
}

// ---------------- MFMA attention: 8 waves + setprio + phase-B bias prefetch ----------------
// Swapped QK^T, zero-shuffle PV, split-K online softmax. Phase-B bias loads issued
// BEFORE phase-A compute (~1500cy cover) -> removes one VMEM wait per qt-iteration.
__global__ __launch_bounds__(512) void k_attn(const __hip_bfloat16* __restrict__ qkvi,
                                              const float* __restrict__ biasws,
                                              __hip_bfloat16* __restrict__ Ows) {
  __shared__ unsigned short Ks[352][40];      // 28160 B
  __shared__ unsigned short Vt[32][360];      // 23040 B, V transposed+permuted [d][vperm(n)]
  const int bid = blockIdx.x;
  const int h = bid / (2 * BW);
  const int sb = bid % (2 * BW);
  const int s = sb >> 7;
  const int b = sb & 127;
  const int so = 1 - s;
  const size_t qbase = (((size_t)(s * 3 + 0) * BW + b) * NHEAD + h) * (size_t)NTOK * HDIM;
  const size_t kbase = (((size_t)(so * 3 + 1) * BW + b) * NHEAD + h) * (size_t)NTOK * HDIM;
  const size_t vbase = (((size_t)(so * 3 + 2) * BW + b) * NHEAD + h) * (size_t)NTOK * HDIM;
  const unsigned short* __restrict__ qp = (const unsigned short*)qkvi;
  unsigned short* __restrict__ op = (unsigned short*)Ows;
  const float* __restrict__ bh = biasws + (size_t)h * BNN;
  const int tid = threadIdx.x;

  // stage K (bf16 copy, zero-pad rows 343..351)
  for (int idx = tid; idx < 352 * 4; idx += 512) {
    const int n = idx >> 2, d0 = (idx & 3) * 8;
    uint4 v = {0u, 0u, 0u, 0u};
    if (n < NTOK) v = *reinterpret_cast<const uint4*>(qp + kbase + (size_t)n * HDIM + d0);
    *reinterpret_cast<uint4*>(&Ks[n][d0]) = v;
  }
  // stage V transposed with pi baked in: Vt[d][vperm(n)] = V[n][d]
  for (int idx = tid; idx < NTOK * 4; idx += 512) {
    const int n = idx >> 2, d0 = (idx & 3) * 8;
    const int np = vperm(n);
    const uint4 v = *reinterpret_cast<const uint4*>(qp + vbase + (size_t)n * HDIM + d0);
    const unsigned short* ep = reinterpret_cast<const unsigned short*>(&v);
#pragma unroll
    for (int e = 0; e < 8; ++e) Vt[d0 + e][np] = ep[e];
  }
  for (int idx = tid; idx < 32 * 9; idx += 512)
    Vt[idx / 9][vperm(NTOK + idx % 9)] = 0;
  __syncthreads();

  const int lane = tid & 63, w = tid >> 6;    // 8 waves
  const int c16 = lane & 15, q4 = lane >> 4;
  const bool loSel = (q4 < 2);   // kt=21 bias-load clamp (stay inside row stride)

  for (int qt = w; qt < 22; qt += 8) {
    const int iq = qt * 16 + c16;                     // this lane's softmax row
    const int iqc = (iq < NTOK) ? iq : NTOK - 1;      // clamp (dup rows masked by O-write)
    const short8 qf = *reinterpret_cast<const short8*>(qp + qbase + (size_t)iqc * HDIM + q4 * 8);
    const float* brow = bh + (size_t)iqc * BSTR;

    // prefetch phase-B bias NOW; arrives under phase-A compute (T14)
    float4 bB[10];
#pragma unroll
    for (int k2 = 0; k2 < 10; ++k2) {
      const int kt = 12 + k2;
      const int jb = (kt < 21) ? (kt * 16 + q4 * 4) : (336 + (loSel ? q4 * 4 : 0));
      bB[k2] = *reinterpret_cast<const float4*>(brow + jb);
    }

    f32x4 o0 = {0.f, 0.f, 0.f, 0.f}, o1 = {0.f, 0.f, 0.f, 0.f};
    float mA, sumA;   // phase-A row max (cross-lane), per-lane partial sum

    // ================= Phase A: kt 0..11 =================
    {
      f32x4 acc[12];
#pragma unroll
      for (int kt = 0; kt < 12; ++kt) {
        const float4 bv = *reinterpret_cast<const float4*>(brow + kt * 16 + q4 * 4);
        acc[kt] = f32x4{bv.x, bv.y, bv.z, bv.w};
      }
      __builtin_amdgcn_s_setprio(1);
#pragma unroll
      for (int kt = 0; kt < 12; ++kt) {
        const short8 kf = *reinterpret_cast<const short8*>(&Ks[kt * 16 + c16][q4 * 8]);
        acc[kt] = __builtin_amdgcn_mfma_f32_16x16x32_bf16(kf, qf, acc[kt], 0, 0, 0);
      }
      __builtin_amdgcn_s_setprio(0);
      float m0 = acc[0][0], m1 = acc[0][1], m2 = acc[0][2], m3 = acc[0][3];
#pragma unroll
      for (int kt = 1; kt < 12; ++kt) {
        m0 = fmaxf(m0, acc[kt][0]);
        m1 = fmaxf(m1, acc[kt][1]);
        m2 = fmaxf(m2, acc[kt][2]);
        m3 = fmaxf(m3, acc[kt][3]);
      }
      float m = fmaxf(fmaxf(m0, m1), fmaxf(m2, m3));
      m = fmaxf(m, __shfl_xor(m, 16, 64));
      m = fmaxf(m, __shfl_xor(m, 32, 64));
      mA = m;
      float s0 = 0.f, s1 = 0.f, s2 = 0.f, s3 = 0.f;
#pragma unroll
      for (int kt = 0; kt < 12; ++kt) {
        const float p0 = fexp2(acc[kt][0] - m); acc[kt][0] = p0; s0 += p0;
        const float p1 = fexp2(acc[kt][1] - m); acc[kt][1] = p1; s1 += p1;
        const float p2 = fexp2(acc[kt][2] - m); acc[kt][2] = p2; s2 += p2;
        const float p3 = fexp2(acc[kt][3] - m); acc[kt][3] = p3; s3 += p3;
      }
      sumA = (s0 + s1) + (s2 + s3);

      // PV-A: ks 0..5; A-frag own regs, B-frag single b128 (permuted Vt)
      __builtin_amdgcn_s_setprio(1);
#pragma unroll
      for (int ks = 0; ks < 6; ++ks) {
        uint4 pw;
        pw.x = pkpair(acc[2 * ks][0], acc[2 * ks][1]);
        pw.y = pkpair(acc[2 * ks][2], acc[2 * ks][3]);
        pw.z = pkpair(acc[2 * ks + 1][0], acc[2 * ks + 1][1]);
        pw.w = pkpair(acc[2 * ks + 1][2], acc[2 * ks + 1][3]);
        const short8 pf = *reinterpret_cast<const short8*>(&pw);
        const short8 v0 = *reinterpret_cast<const short8*>(&Vt[c16][ks * 32 + q4 * 8]);
        const short8 v1 = *reinterpret_cast<const short8*>(&Vt[16 + c16][ks * 32 + q4 * 8]);
        o0 = __builtin_amdgcn_mfma_f32_16x16x32_bf16(pf, v0, o0, 0, 0, 0);
        o1 = __builtin_amdgcn_mfma_f32_16x16x32_bf16(pf, v1, o1, 0, 0, 0);
      }
      __builtin_amdgcn_s_setprio(0);
    }

    // ================= Phase B: kt 12..21 (bias from prefetched regs) =================
    float rinv;
    {
      f32x4 acc[10];
#pragma unroll
      for (int k2 = 0; k2 < 10; ++k2)
        acc[k2] = f32x4{bB[k2].x, bB[k2].y, bB[k2].z, bB[k2].w};
      __builtin_amdgcn_s_setprio(1);
#pragma unroll
      for (int k2 = 0; k2 < 10; ++k2) {
        const short8 kf = *reinterpret_cast<const short8*>(&Ks[(12 + k2) * 16 + c16][q4 * 8]);
        acc[k2] = __builtin_amdgcn_mfma_f32_16x16x32_bf16(kf, qf, acc[k2], 0, 0, 0);
      }
      __builtin_amdgcn_s_setprio(0);
      // mask invalid j: kt=21 -> j = 336 + q4*4 + r >= 343
#pragma unroll
      for (int r = 0; r < 4; ++r)
        if (q4 * 4 + r >= 7) acc[9][r] = -1e30f;

      float m0 = acc[0][0], m1 = acc[0][1], m2 = acc[0][2], m3 = acc[0][3];
#pragma unroll
      for (int k2 = 1; k2 < 10; ++k2) {
        m0 = fmaxf(m0, acc[k2][0]);
        m1 = fmaxf(m1, acc[k2][1]);
        m2 = fmaxf(m2, acc[k2][2]);
        m3 = fmaxf(m3, acc[k2][3]);
      }
      float m = fmaxf(fmaxf(m0, m1), fmaxf(m2, m3));
      m = fmaxf(m, __shfl_xor(m, 16, 64));
      m = fmaxf(m, __shfl_xor(m, 32, 64));
      m = fmaxf(m, mA);
      const float alpha = fexp2(mA - m);

      float s0 = 0.f, s1 = 0.f, s2 = 0.f, s3 = 0.f;
#pragma unroll
      for (int k2 = 0; k2 < 10; ++k2) {
        const float p0 = fexp2(acc[k2][0] - m); acc[k2][0] = p0; s0 += p0;
        const float p1 = fexp2(acc[k2][1] - m); acc[k2][1] = p1; s1 += p1;
        const float p2 = fexp2(acc[k2][2] - m); acc[k2][2] = p2; s2 += p2;
        const float p3 = fexp2(acc[k2][3] - m); acc[k2][3] = p3; s3 += p3;
      }
      float lanesum = sumA * alpha + ((s0 + s1) + (s2 + s3));
      lanesum += __shfl_xor(lanesum, 16, 64);
      lanesum += __shfl_xor(lanesum, 32, 64);
      rinv = 1.f / lanesum;

      float alphar[4];
#pragma unroll
      for (int r = 0; r < 4; ++r) alphar[r] = __shfl(alpha, q4 * 4 + r, 64);
#pragma unroll
      for (int r = 0; r < 4; ++r) {
        o0[r] *= alphar[r];
        o1[r] *= alphar[r];
      }

      // PV-B: ks 6..10
      __builtin_amdgcn_s_setprio(1);
#pragma unroll
      for (int ks = 6; ks < 11; ++ks) {
        const int k2 = 2 * (ks - 6);
        uint4 pw;
        pw.x = pkpair(acc[k2][0], acc[k2][1]);
        pw.y = pkpair(acc[k2][2], acc[k2][3]);
        pw.z = pkpair(acc[k2 + 1][0], acc[k2 + 1][1]);
        pw.w = pkpair(acc[k2 + 1][2], acc[k2 + 1][3]);
        const short8 pf = *reinterpret_cast<const short8*>(&pw);
        const short8 v0 = *reinterpret_cast<const short8*>(&Vt[c16][ks * 32 + q4 * 8]);
        const short8 v1 = *reinterpret_cast<const short8*>(&Vt[16 + c16][ks * 32 + q4 * 8]);
        o0 = __builtin_amdgcn_mfma_f32_16x16x32_bf16(pf, v0, o0, 0, 0, 0);
        o1 = __builtin_amdgcn_mfma_f32_16x16x32_bf16(pf, v1, o1, 0, 0, 0);
      }
      __builtin_amdgcn_s_setprio(0);
    }

    // O epilogue
    float rsv[4];
#pragma unroll
    for (int r = 0; r < 4; ++r) rsv[r] = __shfl(rinv, q4 * 4 + r, 64);
#pragma unroll
    for (int r = 0; r < 4; ++r) {
      const int i = qt * 16 + q4 * 4 + r;
      if (i < NTOK) {
        const size_t ob = ((size_t)s * TOK + (size_t)b * NTOK + i) * DIMC + h * HDIM;
        op[ob + c16]      = f2bf(o0[r] * rsv[r]);
        op[ob + 16 + c16] = f2bf(o1[r] * rsv[r]);
      }
    }
  }
}

// ---------------- output projection: MFMA bf16, BM=128 + W prefetch (mirrors k_qkv) ----------------
__global__ __launch_bounds__(256) void k_proj(const unsigned short* __restrict__ Oin,
                                              const float* __restrict__ w,
                                              const float* __restrict__ pb,
                                              float* __restrict__ out) {
  __shared__ unsigned short Xs[128][200];   // 51.2 KB
  __shared__ unsigned short Ws[64][200];    // 25.6 KB
  const int R0 = blockIdx.x * 128;
  const int tid = threadIdx.x;
  const int lane = tid & 63, wv = tid >> 6;
  const int c16 = lane & 15, q4 = lane >> 4;
  const int wr = wv >> 1, wc = wv & 1;      // wave: 64-row half x 32-col half

  // stage O rows (already bf16): plain 16B copies
  for (int c = tid; c < 128 * 24; c += 256) {
    const int r = c / 24, k8 = (c % 24) * 8;
    *reinterpret_cast<uint4*>(&Xs[r][k8]) =
        *reinterpret_cast<const uint4*>(&Oin[(size_t)(R0 + r) * DIMC + k8]);
  }

  float4 wa[6], wb[6];
#pragma unroll
  for (int i = 0; i < 6; ++i) {
    const int c = tid + i * 256;
    const int r = c / 24, k8 = (c % 24) * 8;
    const float* p = &w[(size_t)r * DIMC + k8];
    wa[i] = *reinterpret_cast<const float4*>(p);
    wb[i] = *reinterpret_cast<const float4*>(p + 4);
  }

  for (int ct = 0; ct < 3; ++ct) {
    __syncthreads();
#pragma unroll
    for (int i = 0; i < 6; ++i) {
      const int c = tid + i * 256;
      const int r = c / 24, k8 = (c % 24) * 8;
      *reinterpret_cast<uint4*>(&Ws[r][k8]) = pack8bf(wa[i], wb[i]);
    }
    __syncthreads();

    if (ct < 2) {
#pragma unroll
      for (int i = 0; i < 6; ++i) {
        const int c = tid + i * 256;
        const int r = c / 24, k8 = (c % 24) * 8;
        const float* p = &w[(size_t)((ct + 1) * 64 + r) * DIMC + k8];
        wa[i] = *reinterpret_cast<const float4*>(p);
        wb[i] = *reinterpret_cast<const float4*>(p + 4);
      }
    }

    const int colbase = ct * 64 + wc * 32;
    f32x4 acc[2][4];
#pragma unroll
    for (int m = 0; m < 2; ++m) {
      const float4 bb = *reinterpret_cast<const float4*>(&pb[colbase + m * 16 + q4 * 4]);
#pragma unroll
      for (int n = 0; n < 4; ++n) acc[m][n] = f32x4{bb.x, bb.y, bb.z, bb.w};
    }
#pragma unroll
    for (int ks = 0; ks < 6; ++ks) {
      const short8 w0 = *reinterpret_cast<const short8*>(&Ws[wc * 32 + c16][ks * 32 + q4 * 8]);
      const short8 w1 = *reinterpret_cast<const short8*>(&Ws[wc * 32 + 16 + c16][ks * 32 + q4 * 8]);
      short8 xf[4];
#pragma unroll
      for (int n = 0; n < 4; ++n)
        xf[n] = *reinterpret_cast<const short8*>(&Xs[wr * 64 + n * 16 + c16][ks * 32 + q4 * 8]);
#pragma unroll
      for (int n = 0; n < 4; ++n) {
        acc[0][n] = __builtin_amdgcn_mfma_f32_16x16x32_bf16(w0, xf[n], acc[0][n], 0, 0, 0);
        acc[1][n] = __builtin_amdgcn_mfma_f32_16x16x32_bf16(w1, xf[n], acc[1][n], 0, 0, 0);
      }
    }

    // epilogue: thread owns token row x 4 consecutive cols -> float4 stores
#pragma unroll
    for (int m = 0; m < 2; ++m) {
      const int col0 = colbase + m * 16 + q4 * 4;
#pragma unroll
      for (int n = 0; n < 4; ++n) {
        const int row = R0 + wr * 64 + n * 16 + c16;
        float4 ov;
        ov.x = acc[m][n][0];
        ov.y = acc[m][n][1];
        ov.z = acc[m][n][2];
        ov.w = acc[m][n][3];
        *reinterpret_cast<float4*>(&out[(size_t)row * DIMC + col0]) = ov;
      }
    }
  }
}

extern "C" void kernel_launch(void* const* d_in, const int* in_sizes, int n_in,
                              void* d_out, int out_size, void* d_ws, size_t ws_size,
                              hipStream_t stream) {
  const float* x      = (const float*)d_in[0];
  const float* x1     = (const float*)d_in[1];
  const float* qkv_w  = (const float*)d_in[2];
  const float* qkv_b  = (const float*)d_in[3];
  const float* proj_w = (const float*)d_in[4];
  const float* proj_b = (const float*)d_in[5];
  const float* rpb    = (const float*)d_in[6];
  const int*   ridx   = (const int*)d_in[7];
  float* out = (float*)d_out;

  // workspace: qkv bf16 101,154,816 B | O bf16 33,718,272 B | bias f32 (stride 344) 2,831,808 B
  char* ws = (char*)d_ws;
  unsigned short* qkv  = (unsigned short*)ws;
  unsigned short* Ows  = (unsigned short*)(ws + 101154816);
  float*          bws  = (float*)(ws + 101154816 + 33718272);

  k_bias<<<(NN + 255) / 256, 256, 0, stream>>>(rpb, ridx, bws);
  k_qkv<<<M2 / 128, 256, 0, stream>>>(x, x1, qkv_w, qkv_b, qkv);
  k_attn<<<2 * BW * NHEAD, 512, 0, stream>>>((const __hip_bfloat16*)qkv, bws,
                                             (__hip_bfloat16*)Ows);
  k_proj<<<M2 / 128, 256, 0, stream>>>(Ows, proj_w, proj_b, out);
}

// Round 20
// 172.321 us; speedup vs baseline: 1.0675x; 1.0675x over previous
//
#include <hip/hip_runtime.h>
#include <hip/hip_bf16.h>

#define BW 128
#define NTOK 343
#define DIMC 192
#define NHEAD 6
#define HDIM 32
#define TOK (BW * NTOK)      // 43904
#define M2 (2 * TOK)         // 87808
#define NN (NTOK * NTOK)     // 117649
#define BSTR 344             // padded bias row stride (16B-aligned float4 reads)
#define BNN (NTOK * BSTR)    // 117992 per head
#define QSCALE 0.17677669529663687f
#define LOG2E 1.4426950408889634f

typedef unsigned int uint32;
typedef __attribute__((ext_vector_type(8))) short short8;   // 8 bf16 = 4 VGPR
typedef __attribute__((ext_vector_type(4))) float f32x4;

// round-to-nearest-even f32 -> bf16 bits (scalar path)
__device__ __forceinline__ unsigned short f2bf(float f) {
  uint32 u = __float_as_uint(f);
  u += 0x7fffu + ((u >> 16) & 1u);
  return (unsigned short)(u >> 16);
}

// pair pack via v_cvt_pk_bf16_f32 (semantic form; casts beat hand bit-ops)
__device__ __forceinline__ uint32 pkpair(float a, float b) {
  __hip_bfloat162 h = __float22bfloat162_rn(make_float2(a, b));
  uint32 u;
  __builtin_memcpy(&u, &h, 4);
  return u;
}

__device__ __forceinline__ uint4 pack8bf(const float4 a, const float4 b) {
  uint4 pk;
  pk.x = pkpair(a.x, a.y);
  pk.y = pkpair(a.z, a.w);
  pk.z = pkpair(b.x, b.y);
  pk.w = pkpair(b.z, b.w);
  return pk;
}

// native 2^x (v_exp_f32); logits carry log2e factor so this IS softmax's exp
__device__ __forceinline__ float fexp2(float x) {
  float r;
  asm("v_exp_f32 %0, %1" : "=v"(r) : "v"(x));
  return r;
}

// PV k-permutation pi (dot-product k-order invariant; A and B agree):
// within each 32-block: l=(n&31), lo=l&15, hi=l>>4 -> slot (lo>>2)*8 + hi*4 + (lo&3)
__device__ __forceinline__ int vperm(int n) {
  const int base = n & ~31, l = n & 31, lo = l & 15, hi = l >> 4;
  return base + ((lo >> 2) << 3) + (hi << 2) + (lo & 3);
}

// ---------------- bias gather: bias[h][i][j] = rpb[rel_idx[i,j]*NH + h] * log2e ----------------
__global__ void k_bias(const float* __restrict__ rpb, const int* __restrict__ ridx,
                       float* __restrict__ biasws) {
  const int idx = blockIdx.x * 256 + threadIdx.x;
  if (idx < NN) {
    const int r = ridx[idx];
    const int i = idx / NTOK, j = idx % NTOK;
#pragma unroll
    for (int h = 0; h < NHEAD; ++h)
      biasws[h * BNN + i * BSTR + j] = rpb[r * NHEAD + h] * LOG2E;
  }
}

// ---------------- QKV projection: MFMA bf16, BM=128, async W prefetch (T14) ----------------
__global__ __launch_bounds__(256) void k_qkv(const float* __restrict__ x,
                                             const float* __restrict__ x1,
                                             const float* __restrict__ w,
                                             const float* __restrict__ bvec,
                                             unsigned short* __restrict__ qkvo) {
  __shared__ unsigned short Xs[128][200];   // 51.2 KB
  __shared__ unsigned short Ws[64][200];    // 25.6 KB
  const int R0 = blockIdx.x * 128;
  const int s = R0 / TOK;
  const int tokbase = R0 % TOK;
  const float* __restrict__ src = s ? x1 : x;
  const int tid = threadIdx.x;
  const int lane = tid & 63, wv = tid >> 6;
  const int c16 = lane & 15, q4 = lane >> 4;
  const int wr = wv >> 1, wc = wv & 1;      // wave: 64-row half x 32-col half

  int bidxv[4], nnv[4];
#pragma unroll
  for (int n = 0; n < 4; ++n) {
    const int tok = tokbase + wr * 64 + n * 16 + c16;
    bidxv[n] = tok / NTOK;
    nnv[n] = tok % NTOK;
  }

  for (int c = tid; c < 128 * 24; c += 256) {
    const int r = c / 24, k8 = (c % 24) * 8;
    const float* p = &src[(size_t)(tokbase + r) * DIMC + k8];
    const float4 a = *reinterpret_cast<const float4*>(p);
    const float4 b = *reinterpret_cast<const float4*>(p + 4);
    *reinterpret_cast<uint4*>(&Xs[r][k8]) = pack8bf(a, b);
  }

  float4 wa[6], wb[6];
#pragma unroll
  for (int i = 0; i < 6; ++i) {
    const int c = tid + i * 256;
    const int r = c / 24, k8 = (c % 24) * 8;
    const float* p = &w[(size_t)r * DIMC + k8];
    wa[i] = *reinterpret_cast<const float4*>(p);
    wb[i] = *reinterpret_cast<const float4*>(p + 4);
  }

  for (int ct = 0; ct < 9; ++ct) {
    __syncthreads();
#pragma unroll
    for (int i = 0; i < 6; ++i) {
      const int c = tid + i * 256;
      const int r = c / 24, k8 = (c % 24) * 8;
      *reinterpret_cast<uint4*>(&Ws[r][k8]) = pack8bf(wa[i], wb[i]);
    }
    __syncthreads();

    if (ct < 8) {
#pragma unroll
      for (int i = 0; i < 6; ++i) {
        const int c = tid + i * 256;
        const int r = c / 24, k8 = (c % 24) * 8;
        const float* p = &w[(size_t)((ct + 1) * 64 + r) * DIMC + k8];
        wa[i] = *reinterpret_cast<const float4*>(p);
        wb[i] = *reinterpret_cast<const float4*>(p + 4);
      }
    }

    const int colbase = ct * 64 + wc * 32;
    f32x4 acc[2][4];
#pragma unroll
    for (int m = 0; m < 2; ++m) {
      const float4 bb = *reinterpret_cast<const float4*>(&bvec[colbase + m * 16 + q4 * 4]);
#pragma unroll
      for (int n = 0; n < 4; ++n) acc[m][n] = f32x4{bb.x, bb.y, bb.z, bb.w};
    }
#pragma unroll
    for (int ks = 0; ks < 6; ++ks) {
      const short8 w0 = *reinterpret_cast<const short8*>(&Ws[wc * 32 + c16][ks * 32 + q4 * 8]);
      const short8 w1 = *reinterpret_cast<const short8*>(&Ws[wc * 32 + 16 + c16][ks * 32 + q4 * 8]);
      short8 xf[4];
#pragma unroll
      for (int n = 0; n < 4; ++n)
        xf[n] = *reinterpret_cast<const short8*>(&Xs[wr * 64 + n * 16 + c16][ks * 32 + q4 * 8]);
#pragma unroll
      for (int n = 0; n < 4; ++n) {
        acc[0][n] = __builtin_amdgcn_mfma_f32_16x16x32_bf16(w0, xf[n], acc[0][n], 0, 0, 0);
        acc[1][n] = __builtin_amdgcn_mfma_f32_16x16x32_bf16(w1, xf[n], acc[1][n], 0, 0, 0);
      }
    }

    const int t = ct / 3;
    const float qs = (t == 0) ? (QSCALE * LOG2E) : 1.0f;
#pragma unroll
    for (int m = 0; m < 2; ++m) {
      const int col0 = colbase + m * 16 + q4 * 4;
      const int h = (col0 - t * DIMC) / HDIM;
      const int d0 = col0 & (HDIM - 1);
      const size_t hb = ((size_t)(s * 3 + t) * BW) * NHEAD + h;
#pragma unroll
      for (int n = 0; n < 4; ++n) {
        const f32x4 a = acc[m][n];
        uint2 pk;
        pk.x = pkpair(a[0] * qs, a[1] * qs);
        pk.y = pkpair(a[2] * qs, a[3] * qs);
        const size_t ob = ((hb + (size_t)bidxv[n] * NHEAD) * NTOK + nnv[n]) * HDIM + d0;
        *reinterpret_cast<uint2*>(&qkvo[ob]) = pk;
      }
    }
  }
}

// ---------------- MFMA attention: round-18 configuration (measured 87.2-87.5 us) ----------------
// 8 waves + setprio; K LDS + permuted Vt; split-K online softmax; 4-chain reductions.
__global__ __launch_bounds__(512) void k_attn(const __hip_bfloat16* __restrict__ qkvi,
                                              const float* __restrict__ biasws,
                                              __hip_bfloat16* __restrict__ Ows) {
  __shared__ unsigned short Ks[352][40];      // 28160 B
  __shared__ unsigned short Vt[32][360];      // 23040 B, V transposed+permuted [d][vperm(n)]
  const int bid = blockIdx.x;
  const int h = bid / (2 * BW);
  const int sb = bid % (2 * BW);
  const int s = sb >> 7;
  const int b = sb & 127;
  const int so = 1 - s;
  const size_t qbase = (((size_t)(s * 3 + 0) * BW + b) * NHEAD + h) * (size_t)NTOK * HDIM;
  const size_t kbase = (((size_t)(so * 3 + 1) * BW + b) * NHEAD + h) * (size_t)NTOK * HDIM;
  const size_t vbase = (((size_t)(so * 3 + 2) * BW + b) * NHEAD + h) * (size_t)NTOK * HDIM;
  const unsigned short* __restrict__ qp = (const unsigned short*)qkvi;
  unsigned short* __restrict__ op = (unsigned short*)Ows;
  const float* __restrict__ bh = biasws + (size_t)h * BNN;
  const int tid = threadIdx.x;

  // stage K (bf16 copy, zero-pad rows 343..351)
  for (int idx = tid; idx < 352 * 4; idx += 512) {
    const int n = idx >> 2, d0 = (idx & 3) * 8;
    uint4 v = {0u, 0u, 0u, 0u};
    if (n < NTOK) v = *reinterpret_cast<const uint4*>(qp + kbase + (size_t)n * HDIM + d0);
    *reinterpret_cast<uint4*>(&Ks[n][d0]) = v;
  }
  // stage V transposed with pi baked in: Vt[d][vperm(n)] = V[n][d]
  for (int idx = tid; idx < NTOK * 4; idx += 512) {
    const int n = idx >> 2, d0 = (idx & 3) * 8;
    const int np = vperm(n);
    const uint4 v = *reinterpret_cast<const uint4*>(qp + vbase + (size_t)n * HDIM + d0);
    const unsigned short* ep = reinterpret_cast<const unsigned short*>(&v);
#pragma unroll
    for (int e = 0; e < 8; ++e) Vt[d0 + e][np] = ep[e];
  }
  for (int idx = tid; idx < 32 * 9; idx += 512)
    Vt[idx / 9][vperm(NTOK + idx % 9)] = 0;
  __syncthreads();

  const int lane = tid & 63, w = tid >> 6;    // 8 waves
  const int c16 = lane & 15, q4 = lane >> 4;
  const bool loSel = (q4 < 2);   // kt=21 bias-load clamp (stay inside row stride)

  for (int qt = w; qt < 22; qt += 8) {
    const int iq = qt * 16 + c16;                     // this lane's softmax row
    const int iqc = (iq < NTOK) ? iq : NTOK - 1;      // clamp (dup rows masked by O-write)
    const short8 qf = *reinterpret_cast<const short8*>(qp + qbase + (size_t)iqc * HDIM + q4 * 8);
    const float* brow = bh + (size_t)iqc * BSTR;

    f32x4 o0 = {0.f, 0.f, 0.f, 0.f}, o1 = {0.f, 0.f, 0.f, 0.f};
    float mA, sumA;   // phase-A row max (cross-lane), per-lane partial sum

    // ================= Phase A: kt 0..11 =================
    {
      f32x4 acc[12];
#pragma unroll
      for (int kt = 0; kt < 12; ++kt) {
        const float4 bv = *reinterpret_cast<const float4*>(brow + kt * 16 + q4 * 4);
        acc[kt] = f32x4{bv.x, bv.y, bv.z, bv.w};
      }
      __builtin_amdgcn_s_setprio(1);
#pragma unroll
      for (int kt = 0; kt < 12; ++kt) {
        const short8 kf = *reinterpret_cast<const short8*>(&Ks[kt * 16 + c16][q4 * 8]);
        acc[kt] = __builtin_amdgcn_mfma_f32_16x16x32_bf16(kf, qf, acc[kt], 0, 0, 0);
      }
      __builtin_amdgcn_s_setprio(0);
      // 4 independent max chains (one per r), then tree-combine
      float m0 = acc[0][0], m1 = acc[0][1], m2 = acc[0][2], m3 = acc[0][3];
#pragma unroll
      for (int kt = 1; kt < 12; ++kt) {
        m0 = fmaxf(m0, acc[kt][0]);
        m1 = fmaxf(m1, acc[kt][1]);
        m2 = fmaxf(m2, acc[kt][2]);
        m3 = fmaxf(m3, acc[kt][3]);
      }
      float m = fmaxf(fmaxf(m0, m1), fmaxf(m2, m3));
      m = fmaxf(m, __shfl_xor(m, 16, 64));
      m = fmaxf(m, __shfl_xor(m, 32, 64));
      mA = m;
      // 4 independent sum chains (chain depth 12, not 48)
      float s0 = 0.f, s1 = 0.f, s2 = 0.f, s3 = 0.f;
#pragma unroll
      for (int kt = 0; kt < 12; ++kt) {
        const float p0 = fexp2(acc[kt][0] - m); acc[kt][0] = p0; s0 += p0;
        const float p1 = fexp2(acc[kt][1] - m); acc[kt][1] = p1; s1 += p1;
        const float p2 = fexp2(acc[kt][2] - m); acc[kt][2] = p2; s2 += p2;
        const float p3 = fexp2(acc[kt][3] - m); acc[kt][3] = p3; s3 += p3;
      }
      sumA = (s0 + s1) + (s2 + s3);

      // PV-A: ks 0..5; A-frag own regs, B-frag single b128 (permuted Vt)
      __builtin_amdgcn_s_setprio(1);
#pragma unroll
      for (int ks = 0; ks < 6; ++ks) {
        uint4 pw;
        pw.x = pkpair(acc[2 * ks][0], acc[2 * ks][1]);
        pw.y = pkpair(acc[2 * ks][2], acc[2 * ks][3]);
        pw.z = pkpair(acc[2 * ks + 1][0], acc[2 * ks + 1][1]);
        pw.w = pkpair(acc[2 * ks + 1][2], acc[2 * ks + 1][3]);
        const short8 pf = *reinterpret_cast<const short8*>(&pw);
        const short8 v0 = *reinterpret_cast<const short8*>(&Vt[c16][ks * 32 + q4 * 8]);
        const short8 v1 = *reinterpret_cast<const short8*>(&Vt[16 + c16][ks * 32 + q4 * 8]);
        o0 = __builtin_amdgcn_mfma_f32_16x16x32_bf16(pf, v0, o0, 0, 0, 0);
        o1 = __builtin_amdgcn_mfma_f32_16x16x32_bf16(pf, v1, o1, 0, 0, 0);
      }
      __builtin_amdgcn_s_setprio(0);
    }

    // ================= Phase B: kt 12..21 =================
    float rinv;
    {
      f32x4 acc[10];
#pragma unroll
      for (int k2 = 0; k2 < 10; ++k2) {
        const int kt = 12 + k2;
        const int jb = (kt < 21) ? (kt * 16 + q4 * 4) : (336 + (loSel ? q4 * 4 : 0));
        const float4 bv = *reinterpret_cast<const float4*>(brow + jb);
        acc[k2] = f32x4{bv.x, bv.y, bv.z, bv.w};
      }
      __builtin_amdgcn_s_setprio(1);
#pragma unroll
      for (int k2 = 0; k2 < 10; ++k2) {
        const short8 kf = *reinterpret_cast<const short8*>(&Ks[(12 + k2) * 16 + c16][q4 * 8]);
        acc[k2] = __builtin_amdgcn_mfma_f32_16x16x32_bf16(kf, qf, acc[k2], 0, 0, 0);
      }
      __builtin_amdgcn_s_setprio(0);
      // mask invalid j: kt=21 -> j = 336 + q4*4 + r >= 343
#pragma unroll
      for (int r = 0; r < 4; ++r)
        if (q4 * 4 + r >= 7) acc[9][r] = -1e30f;

      float m0 = acc[0][0], m1 = acc[0][1], m2 = acc[0][2], m3 = acc[0][3];
#pragma unroll
      for (int k2 = 1; k2 < 10; ++k2) {
        m0 = fmaxf(m0, acc[k2][0]);
        m1 = fmaxf(m1, acc[k2][1]);
        m2 = fmaxf(m2, acc[k2][2]);
        m3 = fmaxf(m3, acc[k2][3]);
      }
      float m = fmaxf(fmaxf(m0, m1), fmaxf(m2, m3));
      m = fmaxf(m, __shfl_xor(m, 16, 64));
      m = fmaxf(m, __shfl_xor(m, 32, 64));
      m = fmaxf(m, mA);
      const float alpha = fexp2(mA - m);

      float s0 = 0.f, s1 = 0.f, s2 = 0.f, s3 = 0.f;
#pragma unroll
      for (int k2 = 0; k2 < 10; ++k2) {
        const float p0 = fexp2(acc[k2][0] - m); acc[k2][0] = p0; s0 += p0;
        const float p1 = fexp2(acc[k2][1] - m); acc[k2][1] = p1; s1 += p1;
        const float p2 = fexp2(acc[k2][2] - m); acc[k2][2] = p2; s2 += p2;
        const float p3 = fexp2(acc[k2][3] - m); acc[k2][3] = p3; s3 += p3;
      }
      float lanesum = sumA * alpha + ((s0 + s1) + (s2 + s3));
      lanesum += __shfl_xor(lanesum, 16, 64);
      lanesum += __shfl_xor(lanesum, 32, 64);
      rinv = 1.f / lanesum;

      float alphar[4];
#pragma unroll
      for (int r = 0; r < 4; ++r) alphar[r] = __shfl(alpha, q4 * 4 + r, 64);
#pragma unroll
      for (int r = 0; r < 4; ++r) {
        o0[r] *= alphar[r];
        o1[r] *= alphar[r];
      }

      // PV-B: ks 6..10
      __builtin_amdgcn_s_setprio(1);
#pragma unroll
      for (int ks = 6; ks < 11; ++ks) {
        const int k2 = 2 * (ks - 6);
        uint4 pw;
        pw.x = pkpair(acc[k2][0], acc[k2][1]);
        pw.y = pkpair(acc[k2][2], acc[k2][3]);
        pw.z = pkpair(acc[k2 + 1][0], acc[k2 + 1][1]);
        pw.w = pkpair(acc[k2 + 1][2], acc[k2 + 1][3]);
        const short8 pf = *reinterpret_cast<const short8*>(&pw);
        const short8 v0 = *reinterpret_cast<const short8*>(&Vt[c16][ks * 32 + q4 * 8]);
        const short8 v1 = *reinterpret_cast<const short8*>(&Vt[16 + c16][ks * 32 + q4 * 8]);
        o0 = __builtin_amdgcn_mfma_f32_16x16x32_bf16(pf, v0, o0, 0, 0, 0);
        o1 = __builtin_amdgcn_mfma_f32_16x16x32_bf16(pf, v1, o1, 0, 0, 0);
      }
      __builtin_amdgcn_s_setprio(0);
    }

    // O epilogue
    float rsv[4];
#pragma unroll
    for (int r = 0; r < 4; ++r) rsv[r] = __shfl(rinv, q4 * 4 + r, 64);
#pragma unroll
    for (int r = 0; r < 4; ++r) {
      const int i = qt * 16 + q4 * 4 + r;
      if (i < NTOK) {
        const size_t ob = ((size_t)s * TOK + (size_t)b * NTOK + i) * DIMC + h * HDIM;
        op[ob + c16]      = f2bf(o0[r] * rsv[r]);
        op[ob + 16 + c16] = f2bf(o1[r] * rsv[r]);
      }
    }
  }
}

// ---------------- output projection: MFMA bf16, BM=128 + W prefetch (round-19 win, kept) ----------------
__global__ __launch_bounds__(256) void k_proj(const unsigned short* __restrict__ Oin,
                                              const float* __restrict__ w,
                                              const float* __restrict__ pb,
                                              float* __restrict__ out) {
  __shared__ unsigned short Xs[128][200];   // 51.2 KB
  __shared__ unsigned short Ws[64][200];    // 25.6 KB
  const int R0 = blockIdx.x * 128;
  const int tid = threadIdx.x;
  const int lane = tid & 63, wv = tid >> 6;
  const int c16 = lane & 15, q4 = lane >> 4;
  const int wr = wv >> 1, wc = wv & 1;      // wave: 64-row half x 32-col half

  // stage O rows (already bf16): plain 16B copies
  for (int c = tid; c < 128 * 24; c += 256) {
    const int r = c / 24, k8 = (c % 24) * 8;
    *reinterpret_cast<uint4*>(&Xs[r][k8]) =
        *reinterpret_cast<const uint4*>(&Oin[(size_t)(R0 + r) * DIMC + k8]);
  }

  float4 wa[6], wb[6];
#pragma unroll
  for (int i = 0; i < 6; ++i) {
    const int c = tid + i * 256;
    const int r = c / 24, k8 = (c % 24) * 8;
    const float* p = &w[(size_t)r * DIMC + k8];
    wa[i] = *reinterpret_cast<const float4*>(p);
    wb[i] = *reinterpret_cast<const float4*>(p + 4);
  }

  for (int ct = 0; ct < 3; ++ct) {
    __syncthreads();
#pragma unroll
    for (int i = 0; i < 6; ++i) {
      const int c = tid + i * 256;
      const int r = c / 24, k8 = (c % 24) * 8;
      *reinterpret_cast<uint4*>(&Ws[r][k8]) = pack8bf(wa[i], wb[i]);
    }
    __syncthreads();

    if (ct < 2) {
#pragma unroll
      for (int i = 0; i < 6; ++i) {
        const int c = tid + i * 256;
        const int r = c / 24, k8 = (c % 24) * 8;
        const float* p = &w[(size_t)((ct + 1) * 64 + r) * DIMC + k8];
        wa[i] = *reinterpret_cast<const float4*>(p);
        wb[i] = *reinterpret_cast<const float4*>(p + 4);
      }
    }

    const int colbase = ct * 64 + wc * 32;
    f32x4 acc[2][4];
#pragma unroll
    for (int m = 0; m < 2; ++m) {
      const float4 bb = *reinterpret_cast<const float4*>(&pb[colbase + m * 16 + q4 * 4]);
#pragma unroll
      for (int n = 0; n < 4; ++n) acc[m][n] = f32x4{bb.x, bb.y, bb.z, bb.w};
    }
#pragma unroll
    for (int ks = 0; ks < 6; ++ks) {
      const short8 w0 = *reinterpret_cast<const short8*>(&Ws[wc * 32 + c16][ks * 32 + q4 * 8]);
      const short8 w1 = *reinterpret_cast<const short8*>(&Ws[wc * 32 + 16 + c16][ks * 32 + q4 * 8]);
      short8 xf[4];
#pragma unroll
      for (int n = 0; n < 4; ++n)
        xf[n] = *reinterpret_cast<const short8*>(&Xs[wr * 64 + n * 16 + c16][ks * 32 + q4 * 8]);
#pragma unroll
      for (int n = 0; n < 4; ++n) {
        acc[0][n] = __builtin_amdgcn_mfma_f32_16x16x32_bf16(w0, xf[n], acc[0][n], 0, 0, 0);
        acc[1][n] = __builtin_amdgcn_mfma_f32_16x16x32_bf16(w1, xf[n], acc[1][n], 0, 0, 0);
      }
    }

    // epilogue: thread owns token row x 4 consecutive cols -> float4 stores
#pragma unroll
    for (int m = 0; m < 2; ++m) {
      const int col0 = colbase + m * 16 + q4 * 4;
#pragma unroll
      for (int n = 0; n < 4; ++n) {
        const int row = R0 + wr * 64 + n * 16 + c16;
        float4 ov;
        ov.x = acc[m][n][0];
        ov.y = acc[m][n][1];
        ov.z = acc[m][n][2];
        ov.w = acc[m][n][3];
        *reinterpret_cast<float4*>(&out[(size_t)row * DIMC + col0]) = ov;
      }
    }
  }
}

extern "C" void kernel_launch(void* const* d_in, const int* in_sizes, int n_in,
                              void* d_out, int out_size, void* d_ws, size_t ws_size,
                              hipStream_t stream) {
  const float* x      = (const float*)d_in[0];
  const float* x1     = (const float*)d_in[1];
  const float* qkv_w  = (const float*)d_in[2];
  const float* qkv_b  = (const float*)d_in[3];
  const float* proj_w = (const float*)d_in[4];
  const float* proj_b = (const float*)d_in[5];
  const float* rpb    = (const float*)d_in[6];
  const int*   ridx   = (const int*)d_in[7];
  float* out = (float*)d_out;

  // workspace: qkv bf16 101,154,816 B | O bf16 33,718,272 B | bias f32 (stride 344) 2,831,808 B
  char* ws = (char*)d_ws;
  unsigned short* qkv  = (unsigned short*)ws;
  unsigned short* Ows  = (unsigned short*)(ws + 101154816);
  float*          bws  = (float*)(ws + 101154816 + 33718272);

  k_bias<<<(NN + 255) / 256, 256, 0, stream>>>(rpb, ridx, bws);
  k_qkv<<<M2 / 128, 256, 0, stream>>>(x, x1, qkv_w, qkv_b, qkv);
  k_attn<<<2 * BW * NHEAD, 512, 0, stream>>>((const __hip_bfloat16*)qkv, bws,
                                             (__hip_bfloat16*)Ows);
  k_proj<<<M2 / 128, 256, 0, stream>>>(Ows, proj_w, proj_b, out);
}